// Round 5
// baseline (445.297 us; speedup 1.0000x reference)
//
#include <hip/hip_runtime.h>

#define N_PMT 180
#define N_PMT4 45            // 180 floats = 45 float4 per vis row (720 B)
#define N_CLUSTERS 128
#define NSLAB 4096           // slab = vox >> 6  (one (iy,iz) column of 64 x-voxels)
#define NKEYS (NSLAB * N_CLUSTERS)   // 524288 sort keys: slab*128 + cluster
#define SPB 16               // slabs per k_slice block (4096 / 256)
#define GBLK 256             // k_slice blocks (1 per CU)
#define GT 1024              // k_slice threads (16 waves)
#define CPW 8                // clusters per wave (128 / 16)
#define VT4 (64 * N_PMT4)    // 2880 float4 per slab vis tile (46,080 B)
#define BLOCK 256
#define NWAVE (BLOCK / 64)

// ---- workspace layout (bytes) ----
// 0        : int   offsC[129]          (reserve 1024)
// 1024     : float dxc[128]            (reserve 1024)
// 2048     : int   ghist[NKEYS]        (2,097,152)
// 2099200  : int   cur[NKEYS]          (2,097,152)
// 4196352  : int   bsum[512]           (reserve 2048)
// 4198400  : int   bo[NKEYS+1]         (reserve 2,097,168)
// 6295568  : uint2 vq[n]               (packed key<<6|ix, q_bits)
// +8n      : uint2 sorted[n]
// +8n      : float partial[GBLK][128][180]   (23,592,960, if ws permits)

__global__ void prep_kernel(const float* __restrict__ dx,
                            const int* __restrict__ sizes,
                            const float* __restrict__ dx_ranges,
                            int* __restrict__ offsC,
                            float* __restrict__ dxc) {
    __shared__ int s[N_CLUSTERS];
    const int t = threadIdx.x;      // 128 threads
    s[t] = sizes[t];
    float lo = dx_ranges[2 * t];
    float hi = dx_ranges[2 * t + 1];
    dxc[t] = fminf(fmaxf(dx[t], lo), hi);
    __syncthreads();
    int acc = 0;
    for (int i = 0; i < t; ++i) acc += s[i];
    offsC[t] = acc;
    if (t == N_CLUSTERS - 1) offsC[N_CLUSTERS] = acc + s[t];
}

// ---- pass 1: voxelize + global histogram over (slab, cluster) keys ---------
__global__ __launch_bounds__(512) void k_hist(
    const float4* __restrict__ batch,
    const int*    __restrict__ offsC,
    const float*  __restrict__ dxc,
    const int n,
    uint2* __restrict__ vq,
    int*   __restrict__ ghist) {

    __shared__ int   so[N_CLUSTERS + 1];
    __shared__ float sd[N_CLUSTERS];
    const int t = threadIdx.x;
    if (t < N_CLUSTERS + 1) so[t] = offsC[t];
    if (t < N_CLUSTERS) sd[t] = dxc[t];
    __syncthreads();

    const int i = blockIdx.x * 512 + t;
    if (i >= n) return;
    int lo = 0, hi = N_CLUSTERS - 1;
    #pragma unroll
    for (int s = 0; s < 7; ++s) {
        const int mid = (lo + hi + 1) >> 1;
        if (i >= so[mid]) lo = mid; else hi = mid - 1;
    }
    const float4 pd = batch[i];
    const int ix = max(0, min(63, (int)floorf(pd.x + sd[lo])));
    const int iy = max(0, min(63, (int)floorf(pd.y)));
    const int iz = max(0, min(63, (int)floorf(pd.z)));
    const int slab = iy + 64 * iz;                 // = vox >> 6
    const int key  = slab * N_CLUSTERS + lo;       // < 524288 (19 bits)
    vq[i] = make_uint2(((unsigned)key << 6) | (unsigned)ix, __float_as_uint(pd.w));
    atomicAdd(&ghist[key], 1);
}

// ---- pass 2a: per-1024-chunk block sums ------------------------------------
__global__ __launch_bounds__(1024) void k_bsum(const int* __restrict__ ghist,
                                               int* __restrict__ bsum) {
    __shared__ int red[1024];
    const int t = threadIdx.x;
    red[t] = ghist[blockIdx.x * 1024 + t];
    __syncthreads();
    for (int d = 512; d > 0; d >>= 1) {
        if (t < d) red[t] += red[t + d];
        __syncthreads();
    }
    if (t == 0) bsum[blockIdx.x] = red[0];
}

// ---- pass 2b: exclusive scan -> bo (boundaries) and cur (scatter cursors) --
__global__ __launch_bounds__(1024) void k_scan(const int* __restrict__ ghist,
                                               const int* __restrict__ bsum,
                                               int* __restrict__ bo,
                                               int* __restrict__ cur) {
    __shared__ int sA[1024], sB[1024];
    const int b = blockIdx.x, t = threadIdx.x;
    // scan the 512 block sums to get this block's global prefix
    if (t < 512) sA[t] = bsum[t];
    __syncthreads();
    int* s1 = sA; int* s2 = sB;
    for (int d = 1; d < 512; d <<= 1) {
        if (t < 512) s2[t] = s1[t] + (t >= d ? s1[t - d] : 0);
        __syncthreads();
        int* tmp = s1; s1 = s2; s2 = tmp;
    }
    const int blockPrefix = (b == 0) ? 0 : s1[b - 1];
    const int idx = b * 1024 + t;
    const int h = ghist[idx];
    __syncthreads();                       // blockPrefix extracted; reuse LDS
    s1[t] = h;
    __syncthreads();
    for (int d = 1; d < 1024; d <<= 1) {
        s2[t] = s1[t] + (t >= d ? s1[t - d] : 0);
        __syncthreads();
        int* tmp = s1; s1 = s2; s2 = tmp;
    }
    const int excl = s1[t] - h + blockPrefix;
    bo[idx] = excl;
    cur[idx] = excl;
    if (idx == NKEYS - 1) bo[NKEYS] = excl + h;
}

// ---- pass 3: scatter into slab-major sorted order --------------------------
__global__ __launch_bounds__(512) void k_scatter(
    const uint2* __restrict__ vq,
    int*   __restrict__ cur,
    const int n,
    uint2* __restrict__ sorted) {
    const int i = blockIdx.x * 512 + threadIdx.x;
    if (i >= n) return;
    const uint2 e = vq[i];
    const int pos = atomicAdd(&cur[e.x >> 6], 1);
    sorted[pos] = e;
}

// ---- gather: LDS vis slab + T14 issue-early/write-late next-slab prefetch --
__global__ __launch_bounds__(GT) void k_slice(
    const uint2*  __restrict__ sorted,
    const float4* __restrict__ vis4,
    const int*    __restrict__ bo,
    float* __restrict__ out,
    float* __restrict__ partial,
    const int usePartial) {

    __shared__ __align__(16) float4 vtile[VT4];        // 46,080 B
    __shared__ int ofs[SPB * N_CLUSTERS + 1];          //  8,196 B

    const int b = blockIdx.x, t = threadIdx.x;
    const int wave = t >> 6, lane = t & 63;
    const int lclamp = min(lane, N_PMT4 - 1);          // lanes 45..63 dup lane 44
    const int cbase = wave * CPW;
    const int S0 = b * SPB;

    for (int i = t; i < SPB * N_CLUSTERS + 1; i += GT)
        ofs[i] = bo[S0 * N_CLUSTERS + i];

    float4 acc[CPW];
    #pragma unroll
    for (int k = 0; k < CPW; ++k) acc[k] = make_float4(0.f, 0.f, 0.f, 0.f);

    // stage slab 0
    for (int i = t; i < VT4; i += GT)
        vtile[i] = vis4[(size_t)S0 * VT4 + i];
    __syncthreads();

    for (int s = 0; s < SPB; ++s) {
        // T14: issue next slab's loads into registers BEFORE consuming
        float4 r0, r1, r2;
        const bool more = (s + 1 < SPB);
        if (more) {
            const size_t nb = (size_t)(S0 + s + 1) * VT4;
            r0 = vis4[nb + t];
            r1 = vis4[nb + t + 1024];
            if (t < VT4 - 2048) r2 = vis4[nb + t + 2048];
        }
        // consume slice s from vtile
        #pragma unroll
        for (int k = 0; k < CPW; ++k) {
            const int c  = cbase + k;
            const int lo = ofs[s * N_CLUSTERS + c];
            const int hi = ofs[s * N_CLUSTERS + c + 1];
            const int m  = hi - lo;
            if (m <= 0) continue;
            uint2 rec = sorted[lo + min(lane, m - 1)];
            const int mm = min(m, 64);
            for (int j = 0; j < mm; ++j) {
                const float qj  = __uint_as_float(__builtin_amdgcn_readlane((int)rec.y, j));
                const int voxl  = __builtin_amdgcn_readlane((int)rec.x, j) & 63;
                const float4 r  = vtile[voxl * N_PMT4 + lclamp];
                acc[k].x = fmaf(r.x, qj, acc[k].x);
                acc[k].y = fmaf(r.y, qj, acc[k].y);
                acc[k].z = fmaf(r.z, qj, acc[k].z);
                acc[k].w = fmaf(r.w, qj, acc[k].w);
            }
            for (int base = lo + 64; base < hi; base += 64) {   // rare long tail
                const int m2 = min(hi - base, 64);
                uint2 rr = sorted[base + min(lane, m2 - 1)];
                for (int j = 0; j < m2; ++j) {
                    const float qj = __uint_as_float(__builtin_amdgcn_readlane((int)rr.y, j));
                    const int voxl = __builtin_amdgcn_readlane((int)rr.x, j) & 63;
                    const float4 r = vtile[voxl * N_PMT4 + lclamp];
                    acc[k].x = fmaf(r.x, qj, acc[k].x);
                    acc[k].y = fmaf(r.y, qj, acc[k].y);
                    acc[k].z = fmaf(r.z, qj, acc[k].z);
                    acc[k].w = fmaf(r.w, qj, acc[k].w);
                }
            }
        }
        __syncthreads();                   // consume done; vtile free
        if (more) {
            vtile[t] = r0;
            vtile[t + 1024] = r1;
            if (t < VT4 - 2048) vtile[t + 2048] = r2;
        }
        __syncthreads();                   // next slab staged
    }

    // flush: each cluster owned by exactly one wave -> plain stores
    if (usePartial) {
        float* pdst = partial + (size_t)b * (N_CLUSTERS * N_PMT);
        if (lane < N_PMT4) {
            #pragma unroll
            for (int k = 0; k < CPW; ++k) {
                float4* d4 = reinterpret_cast<float4*>(pdst + (size_t)(cbase + k) * N_PMT);
                d4[lane] = acc[k];
            }
        }
    } else {
        if (lane < N_PMT4) {
            #pragma unroll
            for (int k = 0; k < CPW; ++k) {
                float* dst = out + (size_t)(cbase + k) * N_PMT + 4 * lane;
                atomicAdd(dst + 0, acc[k].x);
                atomicAdd(dst + 1, acc[k].y);
                atomicAdd(dst + 2, acc[k].z);
                atomicAdd(dst + 3, acc[k].w);
            }
        }
    }
}

__global__ void k_reduce(const float* __restrict__ partial, float* __restrict__ out) {
    const int i = blockIdx.x * 256 + threadIdx.x;
    if (i >= N_CLUSTERS * N_PMT) return;
    float s = 0.f;
    #pragma unroll 4
    for (int b = 0; b < GBLK; ++b)
        s += partial[(size_t)b * (N_CLUSTERS * N_PMT) + i];
    out[i] = s;
}

// ---------------- fallback (unsorted point-major) ----------------
__global__ __launch_bounds__(BLOCK) void gather_kernel(
    const float4* __restrict__ batch,
    const float4* __restrict__ vis4,
    const int*    __restrict__ offsets,
    const float*  __restrict__ dxc,
    float* __restrict__ out) {
    const int b = blockIdx.x;
    const int c = b / 16, sub = b % 16;
    const int start = offsets[c], end = offsets[c + 1];
    const int count = end - start;
    const int chunk = (count + 15) / 16;
    const int s0 = start + sub * chunk;
    const int s1 = min(s0 + chunk, end);
    const int wave = threadIdx.x >> 6, lane = threadIdx.x & 63;
    const int wtotal = s1 - s0;
    const int per = (wtotal + NWAVE - 1) / NWAVE;
    const int ws0 = s0 + wave * per;
    const int ws1 = min(ws0 + per, s1);
    const float dxc_c = dxc[c];
    const bool active = (lane < N_PMT4);
    float4 accE = {0.f, 0.f, 0.f, 0.f};
    for (int base = ws0; base < ws1; base += 64) {
        const int p = base + lane;
        float q = 0.f; int vox = 0;
        if (p < ws1) {
            float4 pd = batch[p];
            int ix = max(0, min(63, (int)floorf(pd.x + dxc_c)));
            int iy = max(0, min(63, (int)floorf(pd.y)));
            int iz = max(0, min(63, (int)floorf(pd.z)));
            vox = ix + 64 * (iy + 64 * iz);
            q = pd.w;
        }
        #pragma unroll
        for (int j = 0; j < 64; ++j) {
            const int   v  = __builtin_amdgcn_readlane(vox, j);
            const float qj = __uint_as_float(__builtin_amdgcn_readlane(__float_as_uint(q), j));
            if (active) {
                float4 r = vis4[(size_t)v * N_PMT4 + lane];
                accE.x = fmaf(r.x, qj, accE.x);
                accE.y = fmaf(r.y, qj, accE.y);
                accE.z = fmaf(r.z, qj, accE.z);
                accE.w = fmaf(r.w, qj, accE.w);
            }
        }
    }
    __shared__ float sacc[N_PMT];
    for (int i = threadIdx.x; i < N_PMT; i += BLOCK) sacc[i] = 0.f;
    __syncthreads();
    if (active) {
        atomicAdd(&sacc[lane * 4 + 0], accE.x);
        atomicAdd(&sacc[lane * 4 + 1], accE.y);
        atomicAdd(&sacc[lane * 4 + 2], accE.z);
        atomicAdd(&sacc[lane * 4 + 3], accE.w);
    }
    __syncthreads();
    for (int i = threadIdx.x; i < N_PMT; i += BLOCK)
        atomicAdd(&out[c * N_PMT + i], sacc[i]);
}

extern "C" void kernel_launch(void* const* d_in, const int* in_sizes, int n_in,
                              void* d_out, int out_size, void* d_ws, size_t ws_size,
                              hipStream_t stream) {
    const float* dx        = (const float*)d_in[0];
    const float* batch     = (const float*)d_in[1];
    const int*   sizes     = (const int*)d_in[2];
    const float* dx_ranges = (const float*)d_in[3];
    const float* vis       = (const float*)d_in[4];
    float* out = (float*)d_out;
    char*  wsb = (char*)d_ws;
    const int n = in_sizes[1] / 4;   // total points

    int*   offsC = (int*)(wsb + 0);
    float* dxc   = (float*)(wsb + 1024);
    int*   ghist = (int*)(wsb + 2048);
    int*   cur   = (int*)(wsb + 2099200);
    int*   bsum  = (int*)(wsb + 4196352);
    int*   bo    = (int*)(wsb + 4198400);
    uint2* vq     = (uint2*)(wsb + 6295568);
    uint2* sorted = (uint2*)(wsb + 6295568 + 8ull * (size_t)n);
    float* partial = (float*)(wsb + 6295568 + 16ull * (size_t)n);
    const size_t need1 = 6295568 + 16ull * (size_t)n;
    const size_t PART_BYTES = (size_t)GBLK * N_CLUSTERS * N_PMT * 4;   // 23,592,960
    const size_t need2 = need1 + PART_BYTES;

    hipMemsetAsync(out, 0, (size_t)out_size * sizeof(float), stream);
    prep_kernel<<<1, N_CLUSTERS, 0, stream>>>(dx, sizes, dx_ranges, offsC, dxc);

    if (ws_size >= need1) {
        const int usePartial = (ws_size >= need2) ? 1 : 0;
        hipMemsetAsync(ghist, 0, (size_t)NKEYS * 4, stream);
        k_hist<<<(n + 511) / 512, 512, 0, stream>>>(
            (const float4*)batch, offsC, dxc, n, vq, ghist);
        k_bsum<<<NKEYS / 1024, 1024, 0, stream>>>(ghist, bsum);
        k_scan<<<NKEYS / 1024, 1024, 0, stream>>>(ghist, bsum, bo, cur);
        k_scatter<<<(n + 511) / 512, 512, 0, stream>>>(vq, cur, n, sorted);
        k_slice<<<GBLK, GT, 0, stream>>>(
            sorted, (const float4*)vis, bo, out,
            usePartial ? partial : out, usePartial);
        if (usePartial)
            k_reduce<<<(N_CLUSTERS * N_PMT + 255) / 256, 256, 0, stream>>>(partial, out);
    } else {
        gather_kernel<<<N_CLUSTERS * 16, BLOCK, 0, stream>>>(
            (const float4*)batch, (const float4*)vis, offsC, dxc, out);
    }
}

// Round 8
// 326.803 us; speedup vs baseline: 1.3626x; 1.3626x over previous
//
#include <hip/hip_runtime.h>

#define N_PMT 180
#define N_PMT4 45            // 180 floats = 45 float4 per vis row (720 B)
#define N_CLUSTERS 128
#define QPB 4                // blocks per cluster -> grid = 512
#define FT 512               // threads per block (8 waves)
#define FW (FT / 64)
#define TILE 2048            // points sorted+gathered per LDS tile
#define NBINS 512            // sort buckets: vox >> 9
#define PIPE 4               // row loads in flight per wave (R0-proven consume loop)

// Single fused kernel: voxelize -> LDS counting sort -> row-gather.
// Only constructs already validated on this harness (R0 gather loop, R1 sort).
__global__ __launch_bounds__(FT) void k_fused(
    const float4* __restrict__ batch,
    const float*  __restrict__ dx,
    const int*    __restrict__ sizes,
    const float*  __restrict__ dx_ranges,
    const float4* __restrict__ vis4,
    float* __restrict__ out) {

    __shared__ int   sSz[N_CLUSTERS];
    __shared__ int   sE0;
    __shared__ uint2 svq[TILE];                // 16 KB (vox, q_bits) unsorted
    __shared__ uint2 ssort[TILE];              // 16 KB bucket-sorted
    __shared__ int   hist[NBINS], cur[NBINS];  // 4 KB
    __shared__ int   scA[NBINS], scB[NBINS];   // 4 KB
    __shared__ float sacc[FW][184];            // 5.75 KB

    const int t = threadIdx.x;
    const int c = blockIdx.x >> 2;             // cluster
    const int quarter = blockIdx.x & 3;

    if (t < N_CLUSTERS) sSz[t] = sizes[t];
    __syncthreads();
    if (t == 0) {
        int acc = 0;
        for (int i = 0; i < c; ++i) acc += sSz[i];
        sE0 = acc;
    }
    __syncthreads();
    const int e0 = sE0;
    const int cnt = sSz[c];
    const float rlo = dx_ranges[2 * c], rhi = dx_ranges[2 * c + 1];
    const float dxcc = fminf(fmaxf(dx[c], rlo), rhi);
    const int qchunk = (cnt + QPB - 1) / QPB;
    const int q0 = min(quarter * qchunk, cnt);
    const int q1 = min(q0 + qchunk, cnt);

    const int wave = t >> 6, lane = t & 63;
    const int lclamp = min(lane, N_PMT4 - 1);  // lanes 45..63 dup lane 44 (branchless)

    float4 accE = {0.f, 0.f, 0.f, 0.f};
    float4 accO = {0.f, 0.f, 0.f, 0.f};

    for (int t0 = q0; t0 < q1; t0 += TILE) {
        const int tcnt = min(TILE, q1 - t0);

        // ---- phase A: load + voxelize into LDS, histogram (vox>>9)
        hist[t & (NBINS - 1)] = 0;             // FT==512==NBINS: one bin per thread
        __syncthreads();
        for (int i = t; i < tcnt; i += FT) {
            const float4 pd = batch[e0 + t0 + i];
            const int ix = max(0, min(63, (int)floorf(pd.x + dxcc)));
            const int iy = max(0, min(63, (int)floorf(pd.y)));
            const int iz = max(0, min(63, (int)floorf(pd.z)));
            const unsigned vox = (unsigned)(ix + 64 * (iy + 64 * iz));
            svq[i] = make_uint2(vox, __float_as_uint(pd.w));
            atomicAdd(&hist[vox >> 9], 1);
        }
        __syncthreads();

        // ---- scan 512 bins (Hillis-Steele, 512 threads) — R1 ksort structure
        scA[t] = hist[t];
        __syncthreads();
        int* s1 = scA; int* s2 = scB;
        for (int d = 1; d < NBINS; d <<= 1) {
            s2[t] = s1[t] + (t >= d ? s1[t - d] : 0);
            __syncthreads();
            int* tmp = s1; s1 = s2; s2 = tmp;
        }
        cur[t] = s1[t] - hist[t];              // exclusive
        __syncthreads();

        // ---- scatter into LDS-sorted order
        for (int i = t; i < tcnt; i += FT) {
            const uint2 e = svq[i];
            const int pos = atomicAdd(&cur[e.x >> 9], 1);
            ssort[pos] = e;
        }
        __syncthreads();

        // ---- phase B: gather rows (R0 k_gather inner loop, verbatim pattern)
        const int per = (tcnt + FW - 1) / FW;
        const int w0 = min(wave * per, tcnt);
        const int w1 = min(w0 + per, tcnt);
        for (int base = w0; base < w1; base += 64) {
            const int p = base + lane;
            uint2 se = (p < w1) ? ssort[p] : make_uint2(0u, 0u);  // pad: q=0
            const int   vox = (int)se.x;
            const float q   = __uint_as_float(se.y);

            float4 rc[PIPE];
            #pragma unroll
            for (int jj = 0; jj < PIPE; ++jj) {
                const int v = __builtin_amdgcn_readlane(vox, jj);
                rc[jj] = vis4[(size_t)v * N_PMT4 + lclamp];
            }
            #pragma unroll
            for (int j0 = 0; j0 < 64; j0 += PIPE) {
                float4 rn[PIPE];
                if (j0 + PIPE < 64) {
                    #pragma unroll
                    for (int jj = 0; jj < PIPE; ++jj) {
                        const int v = __builtin_amdgcn_readlane(vox, j0 + PIPE + jj);
                        rn[jj] = vis4[(size_t)v * N_PMT4 + lclamp];
                    }
                }
                #pragma unroll
                for (int jj = 0; jj < PIPE; ++jj) {
                    const float qq = __uint_as_float(
                        __builtin_amdgcn_readlane(__float_as_uint(q), j0 + jj));
                    if (jj & 1) {
                        accO.x = fmaf(rc[jj].x, qq, accO.x);
                        accO.y = fmaf(rc[jj].y, qq, accO.y);
                        accO.z = fmaf(rc[jj].z, qq, accO.z);
                        accO.w = fmaf(rc[jj].w, qq, accO.w);
                    } else {
                        accE.x = fmaf(rc[jj].x, qq, accE.x);
                        accE.y = fmaf(rc[jj].y, qq, accE.y);
                        accE.z = fmaf(rc[jj].z, qq, accE.z);
                        accE.w = fmaf(rc[jj].w, qq, accE.w);
                    }
                }
                #pragma unroll
                for (int jj = 0; jj < PIPE; ++jj) rc[jj] = rn[jj];  // rename
            }
        }
        __syncthreads();                        // ssort/svq free for next tile
    }

    // ---- flush: per-wave private rows, then one atomic per PMT per block
    if (lane < N_PMT4) {
        sacc[wave][lane * 4 + 0] = accE.x + accO.x;
        sacc[wave][lane * 4 + 1] = accE.y + accO.y;
        sacc[wave][lane * 4 + 2] = accE.z + accO.z;
        sacc[wave][lane * 4 + 3] = accE.w + accO.w;
    }
    __syncthreads();
    for (int i = t; i < N_PMT; i += FT) {
        float s = 0.f;
        #pragma unroll
        for (int w = 0; w < FW; ++w) s += sacc[w][i];
        atomicAdd(&out[c * N_PMT + i], s);
    }
}

extern "C" void kernel_launch(void* const* d_in, const int* in_sizes, int n_in,
                              void* d_out, int out_size, void* d_ws, size_t ws_size,
                              hipStream_t stream) {
    const float* dx        = (const float*)d_in[0];
    const float* batch     = (const float*)d_in[1];
    const int*   sizes     = (const int*)d_in[2];
    const float* dx_ranges = (const float*)d_in[3];
    const float* vis       = (const float*)d_in[4];
    float* out = (float*)d_out;
    (void)d_ws; (void)ws_size; (void)n_in;

    hipMemsetAsync(out, 0, (size_t)out_size * sizeof(float), stream);
    k_fused<<<N_CLUSTERS * QPB, FT, 0, stream>>>(
        (const float4*)batch, dx, sizes, dx_ranges,
        (const float4*)vis, out);
}